// Round 8
// baseline (1045.457 us; speedup 1.0000x reference)
//
#include <hip/hip_runtime.h>
#include <hip/hip_bf16.h>
#include <stdint.h>

// D-MPNN (chemprop MPNEncoder) forward. fp32 in/out; bf16 intermediates, MFMA GEMMs.
// Intermediates use a 320-col padded layout (cols 300..319 == 0).
// R6: gather commutes with GEMM: (amsg[b2a]-msg[b2revb])@W_h = Gh[b2a]-Hm[b2revb],
//   Hm = msg@W_h, Gh = gsum(Hm). Layer = streaming GEMM + gsum + combine.
// R11: BK=64. Five staging structures (R4/R6/R7/R8/R10) all pinned at 10-14%
// MfmaUtil: the invariant is one full-drain barrier per BK=32 step, cost ==
// latency floor (~2500cyc x 10 steps x 12.2 rounds == 127us, exact). Only
// compiler-proof lever: fewer barriers x more work each. BK=64 => 2 K-subtiles
// (40 MFMA, 10 B-loads, 2 gload16) per barrier; K padded to 64-multiples
// (M1: 192, layer: 320, M3: 512; pad cols zeroed).
// R12: fix R11's seg_mean bug - final write was `if (t < 300)` with only 256
// threads, leaving cols 256..299 unwritten (absmax 54). Now strided loop.

#define H_DIM 300
#define HP 320
#define AF_DIM 133
#define BF_DIM 147
#define MAXNB 6

typedef __hip_bfloat16 bf16;
typedef __attribute__((ext_vector_type(8))) short short8;
typedef __attribute__((ext_vector_type(4))) float f32x4;

__device__ __forceinline__ float b2f_raw(unsigned short u) {
    union { unsigned int i; float f; } v; v.i = ((unsigned int)u) << 16; return v.f;
}
__device__ __forceinline__ unsigned short f2b_raw(float f) {
    union { float f; unsigned int i; } v; v.f = f;
    unsigned int x = v.i;
    x += 0x7fffu + ((x >> 16) & 1u);   // RNE
    return (unsigned short)(x >> 16);
}

// async 16B global -> LDS (no VGPR round trip)
__device__ __forceinline__ void gload16(const void* g, void* l) {
    __builtin_amdgcn_global_load_lds(
        (const __attribute__((address_space(1))) unsigned int*)g,
        (__attribute__((address_space(3))) unsigned int*)l,
        16, 0, 0);
}

// ---------------------------------------------------------------------------
// Weight prep: Wt[n][k] (bf16, k-contiguous, n<320, k<nkt*32)
//   k < 320 : s1[k*300 + n]      (k < r1, n < 300)
//   k >= 320: s2[(k-320)*300 + n] (k-320 < r2, n < 300)
// ---------------------------------------------------------------------------
__global__ __launch_bounds__(256) void prep_wt(
    const float* __restrict__ s1, int r1,
    const float* __restrict__ s2, int r2,
    unsigned short* __restrict__ Wt, int nkt)
{
    const int Ktot = nkt * 32;
    const int idx = blockIdx.x * 256 + threadIdx.x;
    if (idx >= 320 * Ktot) return;
    const int n = idx % 320;
    const int k = idx / 320;
    float v = 0.f;
    if (n < H_DIM) {
        if (k < 320) { if (k < r1) v = s1[k * H_DIM + n]; }
        else { const int kk = k - 320; if (kk < r2) v = s2[kk * H_DIM + n]; }
    }
    Wt[n * Ktot + k] = f2b_raw(v);
}

// fp32 [M][W] -> bf16 rows at stride ostride (ushorts), CH 8-col chunks (zero pad)
__global__ __launch_bounds__(256) void prep_cvt(
    const float* __restrict__ in, int W,
    unsigned short* __restrict__ outb, int ostride, int CH, int M)
{
    const int idx = blockIdx.x * 256 + threadIdx.x;
    if (idx >= M * CH) return;
    const int r = idx / CH;
    const int cc = idx - r * CH;
    uint4 o;
    unsigned short* op = (unsigned short*)&o;
#pragma unroll
    for (int j = 0; j < 8; ++j) {
        const int k = cc * 8 + j;
        op[j] = (k < W) ? f2b_raw(in[(long)r * W + k]) : 0;
    }
    *(uint4*)(outb + (long)r * ostride + cc * 8) = o;
}

// ---------------------------------------------------------------------------
// MFMA GEMM, BK=64: out[M][320] (stride 640B) = act(A @ W (+bias)).
// 256 thr / 4 waves; tile 64x320; wave wc owns cols 80wc..+80, all 64 rows:
// acc[4][5] (80 AGPR). NKT2 iters of K=64 (2 sub-tiles of 32). A bf16
// contiguous, row stride ASTR elements (ASTR*2 % 16 == 0). A staged by
// global_load_lds into As[buf][sub][64][64B] (linear; thread t -> row t>>2,
// chunk t&3 of each sub-tile; dest = wave-uniform base + lane*16). One
// __syncthreads per K=64 step drains both async gloads (issued one full
// 40-MFMA block earlier). B global->VGPR per sub-step (Wt L2-resident).
// OOB rows clamped; C-store guards.
// ---------------------------------------------------------------------------
template <int NKT2, int ASTR, bool RELU_A, bool BIAS_RELU>
__global__ __launch_bounds__(256) void mfma_gemm(
    const unsigned short* __restrict__ Ab,
    const unsigned short* __restrict__ Wt,  // [320][NKT2*64]
    const float* __restrict__ bias,
    bf16* __restrict__ out,
    int M)
{
    constexpr int KTOT = NKT2 * 64;

    __shared__ char As[2][2][64 * 64];  // [buf][sub][4KB] double-buffered A
    __shared__ char Cs[16 * 640];       // 10KB epilogue staging

    const int t    = threadIdx.x;
    const int m0   = blockIdx.x * 64;
    const int wc   = t >> 6;          // wave = col strip
    const int lane = t & 63;
    const int l16  = lane & 15;
    const int quad = lane >> 4;

    // A-staging mapping: thread t stages 16B of row t>>2, chunk t&3 per sub-tile
    const int am = t >> 2;
    const int c  = t & 3;
    const int gm = min(m0 + am, M - 1);
    const unsigned short* const agp = Ab + (long)gm * ASTR + c * 8;
    char* const d0s0 = As[0][0] + t * 16;
    char* const d0s1 = As[0][1] + t * 16;
    char* const d1s0 = As[1][0] + t * 16;
    char* const d1s1 = As[1][1] + t * 16;

    auto stage = [&](int kt, int buf) {   // issue 2 async 16B loads (sub0, sub1)
        const unsigned short* g = agp + kt * 64;  // kt*128B
        gload16(g,      buf ? d1s0 : d0s0);
        gload16(g + 32, buf ? d1s1 : d0s1);       // +64B
    };

    auto load_b = [&](int kt, int s, short8* bfr) {
        const int kbase = kt * 64 + s * 32 + quad * 8;
#pragma unroll
        for (int nt = 0; nt < 5; ++nt) {
            const int nn = wc * 80 + nt * 16 + l16;
            bfr[nt] = *(const short8*)(Wt + (long)nn * KTOT + kbase);
        }
    };

    f32x4 acc[4][5];
#pragma unroll
    for (int i = 0; i < 4; ++i)
#pragma unroll
        for (int j = 0; j < 5; ++j) acc[i][j] = (f32x4){0.f, 0.f, 0.f, 0.f};

    // prologue: stage A(0) async, wait once
    stage(0, 0);
    __syncthreads();

    for (int kt = 0; kt < NKT2; ++kt) {
        const char* const abase = (kt & 1) ? As[1][0] : As[0][0];
        short8 b0[5];
        load_b(kt, 0, b0);
        if (kt + 1 < NKT2) stage(kt + 1, (kt + 1) & 1);   // async next K-slab
        // sub-tile 0
        short8 afr[4];
#pragma unroll
        for (int mt = 0; mt < 4; ++mt) {
            short8 v = *(const short8*)(abase + (mt * 16 + l16) * 64 + quad * 16);
            if (RELU_A) {
                unsigned short* rp = (unsigned short*)&v;
#pragma unroll
                for (int j = 0; j < 8; ++j) rp[j] = (rp[j] & 0x8000u) ? 0 : rp[j];
            }
            afr[mt] = v;
        }
#pragma unroll
        for (int nt = 0; nt < 5; ++nt)
#pragma unroll
            for (int mt = 0; mt < 4; ++mt)
                acc[mt][nt] = __builtin_amdgcn_mfma_f32_16x16x32_bf16(
                    afr[mt], b0[nt], acc[mt][nt], 0, 0, 0);
        // sub-tile 1
        short8 b1[5];
        load_b(kt, 1, b1);
#pragma unroll
        for (int mt = 0; mt < 4; ++mt) {
            short8 v = *(const short8*)(abase + 4096 + (mt * 16 + l16) * 64 + quad * 16);
            if (RELU_A) {
                unsigned short* rp = (unsigned short*)&v;
#pragma unroll
                for (int j = 0; j < 8; ++j) rp[j] = (rp[j] & 0x8000u) ? 0 : rp[j];
            }
            afr[mt] = v;
        }
#pragma unroll
        for (int nt = 0; nt < 5; ++nt)
#pragma unroll
            for (int mt = 0; mt < 4; ++mt)
                acc[mt][nt] = __builtin_amdgcn_mfma_f32_16x16x32_bf16(
                    afr[mt], b1[nt], acc[mt][nt], 0, 0, 0);
        __syncthreads();   // drains this iter's async stage (issued 40 MFMAs ago)
    }

    // epilogue: per 16-row strip, LDS transpose -> coalesced 16B stores
    for (int mt = 0; mt < 4; ++mt) {
        __syncthreads();
#pragma unroll
        for (int nt = 0; nt < 5; ++nt) {
            const int col = wc * 80 + nt * 16 + l16;
            float bv = 0.f;
            if (BIAS_RELU) bv = (col < H_DIM) ? bias[col] : 0.f;
#pragma unroll
            for (int r = 0; r < 4; ++r) {
                float v = acc[mt][nt][r] + bv;
                if (BIAS_RELU) v = fmaxf(v, 0.f);
                ((unsigned short*)Cs)[(quad * 4 + r) * HP + col] = f2b_raw(v);
            }
        }
        __syncthreads();
        const int gr0 = m0 + mt * 16;
#pragma unroll
        for (int i = 0; i < 3; ++i) {       // 640 16B-chunks, 256 threads
            const int idx = i * 256 + t;
            if (idx < 640) {
                const int row = idx / 40;   // 40 chunks per 640B row
                if (gr0 + row < M)
                    *(uint4*)((char*)out + (long)(gr0 + row) * 640 + (idx - row * 40) * 16)
                        = *(const uint4*)(Cs + idx * 16);
            }
        }
    }
}

// amsg[a][0:320] = sum_{j<6} msg[a2b[a][j]][0:320]; thread = (atom, 8-col chunk)
// out rows at stride ostride (ushorts)
__global__ __launch_bounds__(256) void gather_sum_kernel(
    const bf16* __restrict__ msg, const int* __restrict__ a2b,
    unsigned short* __restrict__ amsg, int ostride, int n_atoms)
{
    const int idx = blockIdx.x * 256 + threadIdx.x;
    if (idx >= n_atoms * (HP / 8)) return;
    const int a = idx / (HP / 8);
    const int cc = idx - a * (HP / 8);
    float s[8] = {0.f, 0.f, 0.f, 0.f, 0.f, 0.f, 0.f, 0.f};
    const int base = a * MAXNB;
#pragma unroll
    for (int j = 0; j < MAXNB; ++j) {
        const long b = a2b[base + j];
        const uint4 u = *(const uint4*)((const char*)msg + (b * HP + cc * 8) * 2);
        const unsigned short* up = (const unsigned short*)&u;
#pragma unroll
        for (int e = 0; e < 8; ++e) s[e] += b2f_raw(up[e]);
    }
    uint4 r;
    unsigned short* rp = (unsigned short*)&r;
#pragma unroll
    for (int e = 0; e < 8; ++e) rp[e] = f2b_raw(s[e]);
    *(uint4*)(amsg + (long)a * ostride + cc * 8) = r;
}

// msg'[b] = relu(inp[b] + Gh[b2a[b]] - Hm[b2revb[b]]); thread = (bond, 8-col chunk)
__global__ __launch_bounds__(256) void combine_kernel(
    const bf16* __restrict__ inp, const bf16* __restrict__ Gh,
    const bf16* __restrict__ Hm, const int* __restrict__ b2a,
    const int* __restrict__ b2revb, bf16* __restrict__ outm, int n_bonds)
{
    const int idx = blockIdx.x * 256 + threadIdx.x;
    if (idx >= n_bonds * (HP / 8)) return;
    const int b = idx / (HP / 8);
    const int cc = idx - b * (HP / 8);
    const long co = (long)cc * 16;
    const long ra = b2a[b];
    const long rb = b2revb[b];
    const uint4 vi = *(const uint4*)((const char*)inp + (long)b * 640 + co);
    const uint4 vg = *(const uint4*)((const char*)Gh + ra * 640 + co);
    const uint4 vh = *(const uint4*)((const char*)Hm + rb * 640 + co);
    const unsigned short* ip = (const unsigned short*)&vi;
    const unsigned short* gp = (const unsigned short*)&vg;
    const unsigned short* hp = (const unsigned short*)&vh;
    uint4 r;
    unsigned short* rp = (unsigned short*)&r;
#pragma unroll
    for (int e = 0; e < 8; ++e) {
        const float v = b2f_raw(ip[e]) + b2f_raw(gp[e]) - b2f_raw(hp[e]);
        rp[e] = f2b_raw(fmaxf(v, 0.f));
    }
    *(uint4*)((char*)outm + (long)b * 640 + co) = r;
}

// Per-molecule mean; atom_mol sorted -> binary search range, no atomics.
// Vectorized: thread (ra=t/40, c=t%40) accumulates uint4 chunks of rows
// lo+ra, lo+ra+6, ...; LDS reduce over ra; strided col writes (300 > 256!).
__global__ __launch_bounds__(256) void seg_mean_kernel(
    const bf16* __restrict__ hidden, const int* __restrict__ atom_mol,
    float* __restrict__ out, int n_atoms)
{
    const int m = blockIdx.x;
    const int t = threadIdx.x;
    __shared__ int s_lo, s_hi;
    __shared__ float sb[6][320];
    if (t == 0) {
        int lo = 0, hi = n_atoms;
        while (lo < hi) { int mid = (lo + hi) >> 1; if (atom_mol[mid] < m) lo = mid + 1; else hi = mid; }
        s_lo = lo;
        int lo2 = lo; hi = n_atoms;
        while (lo2 < hi) { int mid = (lo2 + hi) >> 1; if (atom_mol[mid] < m + 1) lo2 = mid + 1; else hi = mid; }
        s_hi = lo2;
    }
    __syncthreads();
    const int lo = s_lo, hi = s_hi;
    if (t < 240) {
        const int ra = t / 40;
        const int c  = t - ra * 40;
        float s[8] = {0.f, 0.f, 0.f, 0.f, 0.f, 0.f, 0.f, 0.f};
        for (int a = lo + ra; a < hi; a += 6) {
            const uint4 u = *(const uint4*)((const char*)hidden + (long)a * 640 + c * 16);
            const unsigned short* up = (const unsigned short*)&u;
#pragma unroll
            for (int e = 0; e < 8; ++e) s[e] += b2f_raw(up[e]);
        }
#pragma unroll
        for (int e = 0; e < 8; ++e) sb[ra][c * 8 + e] = s[e];
    }
    __syncthreads();
    const float inv = 1.0f / (float)max(hi - lo, 1);
    for (int cc = t; cc < H_DIM; cc += 256) {   // 300 cols > 256 threads: strided
        float s = 0.f;
#pragma unroll
        for (int r = 0; r < 6; ++r) s += sb[r][cc];
        out[(long)m * H_DIM + cc] = s * inv;
    }
}

extern "C" void kernel_launch(void* const* d_in, const int* in_sizes, int n_in,
                              void* d_out, int out_size, void* d_ws, size_t ws_size,
                              hipStream_t stream)
{
    const float* f_atoms = (const float*)d_in[0];
    const float* f_bonds = (const float*)d_in[1];
    const float* W_i     = (const float*)d_in[2];
    const float* W_h     = (const float*)d_in[3];
    const float* W_o     = (const float*)d_in[4];
    const float* b_o     = (const float*)d_in[5];
    const int*  a2b      = (const int*)d_in[6];
    const int*  b2a      = (const int*)d_in[7];
    const int*  b2revb   = (const int*)d_in[8];
    const int*  atom_mol = (const int*)d_in[9];

    const int n_atoms = in_sizes[0] / AF_DIM;   // 100000
    const int n_bonds = in_sizes[1] / BF_DIM;   // 200000
    const int n_mols  = out_size / H_DIM;       // 4000

    char* ws = (char*)d_ws;
    size_t off = 0;
    auto alloc = [&](size_t bytes) {
        size_t o = off; off += (bytes + 255) & ~(size_t)255; return o;
    };
    bf16* inpB = (bf16*)(ws + alloc((size_t)n_bonds * HP * 2));   // 128 MB (raw inp)
    bf16* msgX = (bf16*)(ws + alloc((size_t)n_bonds * HP * 2));   // 128 MB (msg1/msg2)
    bf16* HmB  = (bf16*)(ws + alloc((size_t)n_bonds * HP * 2));   // 128 MB (Hm per layer)
    bf16* amsg = (bf16*)(ws + alloc((size_t)n_atoms * HP * 2));   //  64 MB (Gh)
    unsigned short* Wt1 = (unsigned short*)(ws + alloc(320 * 192 * 2));
    unsigned short* WtH = (unsigned short*)(ws + alloc(320 * 320 * 2));
    unsigned short* Wt3 = (unsigned short*)(ws + alloc(320 * 512 * 2));
    // Aliases (lifetime-disjoint):
    unsigned short* fb16    = (unsigned short*)HmB;   // f_bonds bf16 [2e5][192] (77MB); dead after M1
    unsigned short* atomcat = (unsigned short*)inpB;  // [1e5][512] (102MB): cols 0-319 gsum,
                                                      // 320-511 f_atoms+pad; prepped after combine-2
    bf16* hidden = HmB;                               // HmB dead after combine-2

    const dim3 blk(256);

    // weight prep (Wt3: amsg part = W_o rows 133.., atom part = W_o rows 0..132)
    prep_wt<<<(320 * 192 + 255) / 256, blk, 0, stream>>>(W_i, BF_DIM, nullptr, 0, Wt1, 6);
    prep_wt<<<(320 * 320 + 255) / 256, blk, 0, stream>>>(W_h, H_DIM, nullptr, 0, WtH, 10);
    prep_wt<<<(320 * 512 + 255) / 256, blk, 0, stream>>>(W_o + (size_t)AF_DIM * H_DIM, H_DIM,
                                                         W_o, AF_DIM, Wt3, 16);

    const int gB = (n_bonds + 63) / 64;   // 3125
    const int gA = (n_atoms + 63) / 64;   // 1563
    const int gG = (n_atoms * (HP / 8) + 255) / 256;
    const int gC = (n_bonds * (HP / 8) + 255) / 256;

    // f_bonds -> bf16 [n_bonds][192] (into HmB area; cols 147.. zero)
    prep_cvt<<<(n_bonds * 24 + 255) / 256, blk, 0, stream>>>(f_bonds, BF_DIM, fb16, 192, 24, n_bonds);

    // inp = f_bonds16 @ W_i (raw; msg0 = relu(inp) folded into layer-1 A-read)
    mfma_gemm<3, 192, false, false><<<gB, blk, 0, stream>>>(fb16, Wt1, nullptr, inpB, n_bonds);

    // layer 1: Hm = relu(inp)@W_h; Gh = gsum(Hm); msg1 = relu(inp + Gh[b2a] - Hm[b2revb])
    mfma_gemm<5, 320, true, false><<<gB, blk, 0, stream>>>(
        (const unsigned short*)inpB, WtH, nullptr, HmB, n_bonds);
    gather_sum_kernel<<<gG, blk, 0, stream>>>(HmB, a2b, (unsigned short*)amsg, HP, n_atoms);
    combine_kernel<<<gC, blk, 0, stream>>>(inpB, amsg, HmB, b2a, b2revb, msgX, n_bonds);

    // layer 2
    mfma_gemm<5, 320, false, false><<<gB, blk, 0, stream>>>(
        (const unsigned short*)msgX, WtH, nullptr, HmB, n_bonds);
    gather_sum_kernel<<<gG, blk, 0, stream>>>(HmB, a2b, (unsigned short*)amsg, HP, n_atoms);
    combine_kernel<<<gC, blk, 0, stream>>>(inpB, amsg, HmB, b2a, b2revb, msgX, n_bonds);

    // readout: atomcat cols 320-511 = f_atoms bf16 + zero pad (inp dead now);
    // cols 0-319 = gsum(msg2)
    prep_cvt<<<(n_atoms * 24 + 255) / 256, blk, 0, stream>>>(f_atoms, AF_DIM, atomcat + 320, 512, 24, n_atoms);
    gather_sum_kernel<<<gG, blk, 0, stream>>>(msgX, a2b, atomcat, 512, n_atoms);
    mfma_gemm<8, 512, false, true><<<gA, blk, 0, stream>>>(atomcat, Wt3, b_o, hidden, n_atoms);

    // per-molecule mean
    seg_mean_kernel<<<n_mols, blk, 0, stream>>>(hidden, atom_mol, (float*)d_out, n_atoms);
}

// Round 9
// 958.045 us; speedup vs baseline: 1.0912x; 1.0912x over previous
//
#include <hip/hip_runtime.h>
#include <hip/hip_bf16.h>
#include <stdint.h>

// D-MPNN (chemprop MPNEncoder) forward. fp32 in/out; bf16 intermediates, MFMA GEMMs.
// Intermediates use a 320-col padded layout (cols 300..319 == 0).
// R6: gather commutes with GEMM: (amsg[b2a]-msg[b2revb])@W_h = Gh[b2a]-Hm[b2revb],
//   Hm = msg@W_h, Gh = gsum(Hm). Layer = streaming GEMM + gsum + combine.
// R13: 16-row waves + B-in-LDS GEMM. R4-R12 all pinned at ~21% occupancy:
// acc[4][5]=80 AGPR + ~96 VGPR = 176 unified regs -> 2 waves/SIMD (gfx950
// unified RF). BK=64 (R12) disproved the barrier-count model: cost scales with
// work, not barriers -> latency-starved at 2 blocks/CU. Fix the ROOT cause:
// wave owns 16 rows x 160 cols -> acc[10] = 40 AGPR, <=128 total -> 4 waves/
// SIMD, 2 independent 8-wave blocks/CU (16 waves). B staged in LDS per K-CHUNK
// (not per K-step; padded +16B stride, 2-way banks = free), K-loop barrier-
// free: 1 contiguous A-load + 10 ds_read_b128 + 10 MFMA per step, compiler
// pipelines with counted lgkmcnt. Epilogue: wave-private LDS transpose (no
// barrier) -> coalesced 16B stores. gather/combine/seg_mean: R12-verified.

#define H_DIM 300
#define HP 320
#define AF_DIM 133
#define BF_DIM 147
#define MAXNB 6

typedef __hip_bfloat16 bf16;
typedef __attribute__((ext_vector_type(8))) short short8;
typedef __attribute__((ext_vector_type(4))) float f32x4;

__device__ __forceinline__ float b2f_raw(unsigned short u) {
    union { unsigned int i; float f; } v; v.i = ((unsigned int)u) << 16; return v.f;
}
__device__ __forceinline__ unsigned short f2b_raw(float f) {
    union { float f; unsigned int i; } v; v.f = f;
    unsigned int x = v.i;
    x += 0x7fffu + ((x >> 16) & 1u);   // RNE
    return (unsigned short)(x >> 16);
}

// ---------------------------------------------------------------------------
// Weight prep: Wt[n][k] (bf16, k-contiguous, n<320, k<nkt*32)
//   k < 320 : s1[k*300 + n]      (k < r1, n < 300)
//   k >= 320: s2[(k-320)*300 + n] (k-320 < r2, n < 300)
// ---------------------------------------------------------------------------
__global__ __launch_bounds__(256) void prep_wt(
    const float* __restrict__ s1, int r1,
    const float* __restrict__ s2, int r2,
    unsigned short* __restrict__ Wt, int nkt)
{
    const int Ktot = nkt * 32;
    const int idx = blockIdx.x * 256 + threadIdx.x;
    if (idx >= 320 * Ktot) return;
    const int n = idx % 320;
    const int k = idx / 320;
    float v = 0.f;
    if (n < H_DIM) {
        if (k < 320) { if (k < r1) v = s1[k * H_DIM + n]; }
        else { const int kk = k - 320; if (kk < r2) v = s2[kk * H_DIM + n]; }
    }
    Wt[n * Ktot + k] = f2b_raw(v);
}

// fp32 [M][W] -> bf16 rows at stride ostride (ushorts), CH 8-col chunks (zero pad)
__global__ __launch_bounds__(256) void prep_cvt(
    const float* __restrict__ in, int W,
    unsigned short* __restrict__ outb, int ostride, int CH, int M)
{
    const int idx = blockIdx.x * 256 + threadIdx.x;
    if (idx >= M * CH) return;
    const int r = idx / CH;
    const int cc = idx - r * CH;
    uint4 o;
    unsigned short* op = (unsigned short*)&o;
#pragma unroll
    for (int j = 0; j < 8; ++j) {
        const int k = cc * 8 + j;
        op[j] = (k < W) ? f2b_raw(in[(long)r * W + k]) : 0;
    }
    *(uint4*)(outb + (long)r * ostride + cc * 8) = o;
}

// ---------------------------------------------------------------------------
// MFMA GEMM, B-in-LDS: out[M][320] (stride 640B) = act(A @ W (+bias)).
// 512 thr / 8 waves. Block tile: 128 rows x 160 cols; blockIdx = (rowblk, colgrp).
// Wave w owns rows 16w..16w+16, all 160 cols: acc[10] = 40 AGPR. A bf16
// contiguous (row stride ASTR elems); per K-step each lane loads its own
// short8: A[(row0+l16)*ASTR + k + quad*8] - no A staging, no K-loop barriers.
// B chunk (160 cols x KCHUNK) staged in LDS, col stride KCHUNK*2+16 B (2-way
// banks). NCHUNKS stages, 2 barriers each. Epilogue: wave-private LDS strip
// (16x160 bf16) -> coalesced 16B global stores; no barrier (own strip only).
// OOB rows clamped; C-store guards.
// ---------------------------------------------------------------------------
template <int KCHUNK, int NCHUNKS, int ASTR, bool RELU_A, bool BIAS_RELU>
__global__ __launch_bounds__(512, 4) void mfma_gemm(
    const unsigned short* __restrict__ Ab,
    const unsigned short* __restrict__ Wt,  // [320][KCHUNK*NCHUNKS]
    const float* __restrict__ bias,
    bf16* __restrict__ out,
    int M)
{
    constexpr int KTOT = KCHUNK * NCHUNKS;
    constexpr int S    = KCHUNK / 32;        // K-steps per chunk
    constexpr int PSTR = KCHUNK * 2 + 16;    // padded col stride (bytes)
    constexpr int BSZ  = 160 * PSTR;
    constexpr int LSZ  = (BSZ > 8 * 5120) ? BSZ : 8 * 5120;
    __shared__ char Ls[LSZ];

    const int t    = threadIdx.x;
    const int wave = t >> 6;
    const int lane = t & 63;
    const int l16  = lane & 15;
    const int quad = lane >> 4;
    const int rb   = blockIdx.x >> 1;
    const int colbase = (blockIdx.x & 1) * 160;
    const int row0 = rb * 128 + wave * 16;

    // per-lane A pointer: own row (clamped), k-offset quad*8
    const unsigned short* const aptr =
        Ab + (long)min(row0 + l16, M - 1) * ASTR + quad * 8;

    f32x4 acc[10];
#pragma unroll
    for (int j = 0; j < 10; ++j) acc[j] = (f32x4){0.f, 0.f, 0.f, 0.f};

    for (int ch = 0; ch < NCHUNKS; ++ch) {
        if (ch) __syncthreads();             // all waves done reading prev chunk
        constexpr int NCK = 160 * (KCHUNK / 8);  // 16B units in chunk
        for (int i = t; i < NCK; i += 512) {
            const int col = i / (KCHUNK / 8);
            const int j   = i - col * (KCHUNK / 8);
            const uint4 v = *(const uint4*)(Wt + (long)(colbase + col) * KTOT
                                            + ch * KCHUNK + j * 8);
            *(uint4*)(Ls + col * PSTR + j * 16) = v;
        }
        __syncthreads();
#pragma unroll
        for (int kt = 0; kt < S; ++kt) {
            short8 a = *(const short8*)(aptr + ch * KCHUNK + kt * 32);
            if (RELU_A) {                    // relu on bf16: clear negatives
                unsigned short* rp = (unsigned short*)&a;
#pragma unroll
                for (int j = 0; j < 8; ++j) rp[j] = (rp[j] & 0x8000u) ? 0 : rp[j];
            }
#pragma unroll
            for (int nt = 0; nt < 10; ++nt) {
                const short8 b = *(const short8*)(
                    Ls + (nt * 16 + l16) * PSTR + (kt * 32 + quad * 8) * 2);
                acc[nt] = __builtin_amdgcn_mfma_f32_16x16x32_bf16(
                    a, b, acc[nt], 0, 0, 0);
            }
        }
    }

    __syncthreads();                          // B region dead; reuse for epilogue
    // wave-private 16x160 bf16 strip (5120 B); no cross-wave sharing -> no barrier
    unsigned short* cs = (unsigned short*)(Ls + wave * 5120);
#pragma unroll
    for (int nt = 0; nt < 10; ++nt) {
        const int col = colbase + nt * 16 + l16;
        float bv = 0.f;
        if (BIAS_RELU) bv = (col < H_DIM) ? bias[col] : 0.f;
#pragma unroll
        for (int r = 0; r < 4; ++r) {
            float v = acc[nt][r] + bv;
            if (BIAS_RELU) v = fmaxf(v, 0.f);
            cs[(quad * 4 + r) * 160 + nt * 16 + l16] = f2b_raw(v);
        }
    }
#pragma unroll
    for (int i = 0; i < 5; ++i) {            // 320 B/row x 16 rows = 320 16B units
        const int idx = i * 64 + lane;
        const int row = idx / 20;
        const int cj  = idx - row * 20;
        const int grow = row0 + row;
        if (grow < M)
            *(uint4*)((char*)out + (long)grow * 640 + colbase * 2 + cj * 16)
                = *(const uint4*)((char*)cs + idx * 16);
    }
}

// amsg[a][0:320] = sum_{j<6} msg[a2b[a][j]][0:320]; thread = (atom, 8-col chunk)
// out rows at stride ostride (ushorts)
__global__ __launch_bounds__(256) void gather_sum_kernel(
    const bf16* __restrict__ msg, const int* __restrict__ a2b,
    unsigned short* __restrict__ amsg, int ostride, int n_atoms)
{
    const int idx = blockIdx.x * 256 + threadIdx.x;
    if (idx >= n_atoms * (HP / 8)) return;
    const int a = idx / (HP / 8);
    const int cc = idx - a * (HP / 8);
    float s[8] = {0.f, 0.f, 0.f, 0.f, 0.f, 0.f, 0.f, 0.f};
    const int base = a * MAXNB;
#pragma unroll
    for (int j = 0; j < MAXNB; ++j) {
        const long b = a2b[base + j];
        const uint4 u = *(const uint4*)((const char*)msg + (b * HP + cc * 8) * 2);
        const unsigned short* up = (const unsigned short*)&u;
#pragma unroll
        for (int e = 0; e < 8; ++e) s[e] += b2f_raw(up[e]);
    }
    uint4 r;
    unsigned short* rp = (unsigned short*)&r;
#pragma unroll
    for (int e = 0; e < 8; ++e) rp[e] = f2b_raw(s[e]);
    *(uint4*)(amsg + (long)a * ostride + cc * 8) = r;
}

// msg'[b] = relu(inp[b] + Gh[b2a[b]] - Hm[b2revb[b]]); thread = (bond, 8-col chunk)
__global__ __launch_bounds__(256) void combine_kernel(
    const bf16* __restrict__ inp, const bf16* __restrict__ Gh,
    const bf16* __restrict__ Hm, const int* __restrict__ b2a,
    const int* __restrict__ b2revb, bf16* __restrict__ outm, int n_bonds)
{
    const int idx = blockIdx.x * 256 + threadIdx.x;
    if (idx >= n_bonds * (HP / 8)) return;
    const int b = idx / (HP / 8);
    const int cc = idx - b * (HP / 8);
    const long co = (long)cc * 16;
    const long ra = b2a[b];
    const long rb = b2revb[b];
    const uint4 vi = *(const uint4*)((const char*)inp + (long)b * 640 + co);
    const uint4 vg = *(const uint4*)((const char*)Gh + ra * 640 + co);
    const uint4 vh = *(const uint4*)((const char*)Hm + rb * 640 + co);
    const unsigned short* ip = (const unsigned short*)&vi;
    const unsigned short* gp = (const unsigned short*)&vg;
    const unsigned short* hp = (const unsigned short*)&vh;
    uint4 r;
    unsigned short* rp = (unsigned short*)&r;
#pragma unroll
    for (int e = 0; e < 8; ++e) {
        const float v = b2f_raw(ip[e]) + b2f_raw(gp[e]) - b2f_raw(hp[e]);
        rp[e] = f2b_raw(fmaxf(v, 0.f));
    }
    *(uint4*)((char*)outm + (long)b * 640 + co) = r;
}

// Per-molecule mean; atom_mol sorted -> binary search range, no atomics.
// Vectorized: thread (ra=t/40, c=t%40) accumulates uint4 chunks of rows
// lo+ra, lo+ra+6, ...; LDS reduce over ra; strided col writes (300 > 256!).
__global__ __launch_bounds__(256) void seg_mean_kernel(
    const bf16* __restrict__ hidden, const int* __restrict__ atom_mol,
    float* __restrict__ out, int n_atoms)
{
    const int m = blockIdx.x;
    const int t = threadIdx.x;
    __shared__ int s_lo, s_hi;
    __shared__ float sb[6][320];
    if (t == 0) {
        int lo = 0, hi = n_atoms;
        while (lo < hi) { int mid = (lo + hi) >> 1; if (atom_mol[mid] < m) lo = mid + 1; else hi = mid; }
        s_lo = lo;
        int lo2 = lo; hi = n_atoms;
        while (lo2 < hi) { int mid = (lo2 + hi) >> 1; if (atom_mol[mid] < m + 1) lo2 = mid + 1; else hi = mid; }
        s_hi = lo2;
    }
    __syncthreads();
    const int lo = s_lo, hi = s_hi;
    if (t < 240) {
        const int ra = t / 40;
        const int c  = t - ra * 40;
        float s[8] = {0.f, 0.f, 0.f, 0.f, 0.f, 0.f, 0.f, 0.f};
        for (int a = lo + ra; a < hi; a += 6) {
            const uint4 u = *(const uint4*)((const char*)hidden + (long)a * 640 + c * 16);
            const unsigned short* up = (const unsigned short*)&u;
#pragma unroll
            for (int e = 0; e < 8; ++e) s[e] += b2f_raw(up[e]);
        }
#pragma unroll
        for (int e = 0; e < 8; ++e) sb[ra][c * 8 + e] = s[e];
    }
    __syncthreads();
    const float inv = 1.0f / (float)max(hi - lo, 1);
    for (int cc = t; cc < H_DIM; cc += 256) {   // 300 cols > 256 threads: strided
        float s = 0.f;
#pragma unroll
        for (int r = 0; r < 6; ++r) s += sb[r][cc];
        out[(long)m * H_DIM + cc] = s * inv;
    }
}

extern "C" void kernel_launch(void* const* d_in, const int* in_sizes, int n_in,
                              void* d_out, int out_size, void* d_ws, size_t ws_size,
                              hipStream_t stream)
{
    const float* f_atoms = (const float*)d_in[0];
    const float* f_bonds = (const float*)d_in[1];
    const float* W_i     = (const float*)d_in[2];
    const float* W_h     = (const float*)d_in[3];
    const float* W_o     = (const float*)d_in[4];
    const float* b_o     = (const float*)d_in[5];
    const int*  a2b      = (const int*)d_in[6];
    const int*  b2a      = (const int*)d_in[7];
    const int*  b2revb   = (const int*)d_in[8];
    const int*  atom_mol = (const int*)d_in[9];

    const int n_atoms = in_sizes[0] / AF_DIM;   // 100000
    const int n_bonds = in_sizes[1] / BF_DIM;   // 200000
    const int n_mols  = out_size / H_DIM;       // 4000

    char* ws = (char*)d_ws;
    size_t off = 0;
    auto alloc = [&](size_t bytes) {
        size_t o = off; off += (bytes + 255) & ~(size_t)255; return o;
    };
    bf16* inpB = (bf16*)(ws + alloc((size_t)n_bonds * HP * 2));   // 128 MB (raw inp)
    bf16* msgX = (bf16*)(ws + alloc((size_t)n_bonds * HP * 2));   // 128 MB (msg1/msg2)
    bf16* HmB  = (bf16*)(ws + alloc((size_t)n_bonds * HP * 2));   // 128 MB (Hm per layer)
    bf16* amsg = (bf16*)(ws + alloc((size_t)n_atoms * HP * 2));   //  64 MB (Gh)
    unsigned short* Wt1 = (unsigned short*)(ws + alloc(320 * 192 * 2));
    unsigned short* WtH = (unsigned short*)(ws + alloc(320 * 320 * 2));
    unsigned short* Wt3 = (unsigned short*)(ws + alloc(320 * 512 * 2));
    // Aliases (lifetime-disjoint):
    unsigned short* fb16    = (unsigned short*)HmB;   // f_bonds bf16 [2e5][192] (77MB); dead after M1
    unsigned short* atomcat = (unsigned short*)inpB;  // [1e5][512] (102MB): cols 0-319 gsum,
                                                      // 320-511 f_atoms+pad; prepped after combine-2
    bf16* hidden = HmB;                               // HmB dead after combine-2

    const dim3 blk(256), blkg(512);

    // weight prep (Wt3: amsg part = W_o rows 133.., atom part = W_o rows 0..132)
    prep_wt<<<(320 * 192 + 255) / 256, blk, 0, stream>>>(W_i, BF_DIM, nullptr, 0, Wt1, 6);
    prep_wt<<<(320 * 320 + 255) / 256, blk, 0, stream>>>(W_h, H_DIM, nullptr, 0, WtH, 10);
    prep_wt<<<(320 * 512 + 255) / 256, blk, 0, stream>>>(W_o + (size_t)AF_DIM * H_DIM, H_DIM,
                                                         W_o, AF_DIM, Wt3, 16);

    const int gB = ((n_bonds + 127) / 128) * 2;   // 1563*2 = 3126
    const int gA = ((n_atoms + 127) / 128) * 2;   // 782*2  = 1564
    const int gG = (n_atoms * (HP / 8) + 255) / 256;
    const int gC = (n_bonds * (HP / 8) + 255) / 256;

    // f_bonds -> bf16 [n_bonds][192] (into HmB area; cols 147.. zero)
    prep_cvt<<<(n_bonds * 24 + 255) / 256, blk, 0, stream>>>(f_bonds, BF_DIM, fb16, 192, 24, n_bonds);

    // inp = f_bonds16 @ W_i (raw; msg0 = relu(inp) folded into layer-1 A-read)
    mfma_gemm<192, 1, 192, false, false><<<gB, blkg, 0, stream>>>(fb16, Wt1, nullptr, inpB, n_bonds);

    // layer 1: Hm = relu(inp)@W_h; Gh = gsum(Hm); msg1 = relu(inp + Gh[b2a] - Hm[b2revb])
    mfma_gemm<160, 2, 320, true, false><<<gB, blkg, 0, stream>>>(
        (const unsigned short*)inpB, WtH, nullptr, HmB, n_bonds);
    gather_sum_kernel<<<gG, blk, 0, stream>>>(HmB, a2b, (unsigned short*)amsg, HP, n_atoms);
    combine_kernel<<<gC, blk, 0, stream>>>(inpB, amsg, HmB, b2a, b2revb, msgX, n_bonds);

    // layer 2
    mfma_gemm<160, 2, 320, false, false><<<gB, blkg, 0, stream>>>(
        (const unsigned short*)msgX, WtH, nullptr, HmB, n_bonds);
    gather_sum_kernel<<<gG, blk, 0, stream>>>(HmB, a2b, (unsigned short*)amsg, HP, n_atoms);
    combine_kernel<<<gC, blk, 0, stream>>>(inpB, amsg, HmB, b2a, b2revb, msgX, n_bonds);

    // readout: atomcat cols 320-511 = f_atoms bf16 + zero pad (inp dead now);
    // cols 0-319 = gsum(msg2)
    prep_cvt<<<(n_atoms * 24 + 255) / 256, blk, 0, stream>>>(f_atoms, AF_DIM, atomcat + 320, 512, 24, n_atoms);
    gather_sum_kernel<<<gG, blk, 0, stream>>>(msgX, a2b, atomcat, 512, n_atoms);
    mfma_gemm<128, 4, 512, false, true><<<gA, blkg, 0, stream>>>(atomcat, Wt3, b_o, hidden, n_atoms);

    // per-molecule mean
    seg_mean_kernel<<<n_mols, blk, 0, stream>>>(hidden, atom_mol, (float*)d_out, n_atoms);
}